// Round 1
// baseline (24.285 us; speedup 1.0000x reference)
//
#include <hip/hip_runtime.h>

// LocalLinearLayer: out[b,o,c] = bias[o] + sum_{j=0..24} W[o, o+j] * xp[b, o+j, c]
// x: [32, 4096, 64] f32, W: [4096, 4120] f32 (only 25-wide band used), b: [4096]
// xp padding: first 12 taps copy x[0..11], last 12 copy x[4084..4095].

constexpr int Lseq = 4096;
constexpr int WIN  = 25;
constexpr int PAD  = 12;          // (WIN-1)/2
constexpr int C4   = 16;          // 64 channels as 16 float4 groups
constexpr int KO   = 8;           // outputs per thread (register sliding window)
constexpr int OG   = 16;          // o-groups per block (256 threads / 16 c4-lanes)
constexpr int O_TILE = KO * OG;   // 128 outputs per block
constexpr int ROWS = KO + WIN - 1; // 32 x-rows per thread

// W is [4096, 4120] row-major; band element (o, j) lives at o*4120 + (o+j) = o*4121 + j.

template <bool EDGE>
__device__ __forceinline__ void compute_tile(
    const float4* __restrict__ x4b,   // x as float4, offset to (batch, channel-group)
    const float*  __restrict__ W,
    const float*  __restrict__ bias,
    float4*       __restrict__ out4b, // out as float4, offset to (batch, channel-group)
    int o0)
{
    float4 acc[KO];
#pragma unroll
    for (int k = 0; k < KO; ++k) {
        float bv = bias[o0 + k];
        acc[k] = make_float4(bv, bv, bv, bv);
    }

    // Per-k integer base offset into W so that weight index = wbase[k] + r (static r).
    int wbase[KO];
#pragma unroll
    for (int k = 0; k < KO; ++k)
        wbase[k] = (o0 + k) * 4121 - k;   // + j where j = r - k

#pragma unroll
    for (int r = 0; r < ROWS; ++r) {
        const int p = o0 + r;             // padded-coordinate tap index
        int t;
        if (EDGE) {
            // p<12: copy of head; p in [12,4108): main; p>=4108: copy of tail
            t = (p < PAD) ? p : ((p < Lseq + PAD) ? (p - PAD) : (p - 2 * PAD));
        } else {
            t = p - PAD;
        }
        const float4 xv = x4b[(size_t)t * C4];
#pragma unroll
        for (int k = 0; k < KO; ++k) {
            const int j = r - k;          // compile-time after unroll
            if (j >= 0 && j < WIN) {
                const float w = W[(size_t)(wbase[k] + r)];
                acc[k].x = fmaf(w, xv.x, acc[k].x);
                acc[k].y = fmaf(w, xv.y, acc[k].y);
                acc[k].z = fmaf(w, xv.z, acc[k].z);
                acc[k].w = fmaf(w, xv.w, acc[k].w);
            }
        }
    }

#pragma unroll
    for (int k = 0; k < KO; ++k)
        out4b[(size_t)(o0 + k) * C4] = acc[k];
}

__global__ __launch_bounds__(256) void lll_kernel(
    const float* __restrict__ x, const float* __restrict__ W,
    const float* __restrict__ bias, float* __restrict__ out)
{
    const int tid = threadIdx.x;
    const int c4  = tid & 15;        // channel group (4 channels)
    const int og  = tid >> 4;        // o-group within block
    const int tiles_per_batch = Lseq / O_TILE;     // 32
    const int b    = blockIdx.x / tiles_per_batch;
    const int tile = blockIdx.x % tiles_per_batch;
    const int o0   = tile * O_TILE + og * KO;

    const float4* x4b  = (const float4*)x + (size_t)b * Lseq * C4 + c4;
    float4*       out4b = (float4*)out    + (size_t)b * Lseq * C4 + c4;

    // Interior iff every tap p in [o0, o0+ROWS) maps linearly: o0 >= PAD and o0+ROWS <= Lseq+PAD
    const bool interior = (o0 >= PAD) && (o0 + ROWS <= Lseq + PAD);
    if (interior)
        compute_tile<false>(x4b, W, bias, out4b, o0);
    else
        compute_tile<true>(x4b, W, bias, out4b, o0);
}

extern "C" void kernel_launch(void* const* d_in, const int* in_sizes, int n_in,
                              void* d_out, int out_size, void* d_ws, size_t ws_size,
                              hipStream_t stream) {
    const float* x    = (const float*)d_in[0];
    const float* W    = (const float*)d_in[1];
    const float* bias = (const float*)d_in[2];
    float*       out  = (float*)d_out;

    const int B = 32;
    const dim3 grid(B * (Lseq / O_TILE));   // 32 * 32 = 1024 blocks
    lll_kernel<<<grid, 256, 0, stream>>>(x, W, bias, out);
}